// Round 1
// baseline (170.105 us; speedup 1.0000x reference)
//
#include <hip/hip_runtime.h>
#include <hip/hip_bf16.h>

typedef __attribute__((ext_vector_type(8))) short bf16x8;
typedef __attribute__((ext_vector_type(4))) float f32x4;

#define B_DIM 16
#define F_DIM 128
#define N_DIM 20000
#define M_DIM 128
#define NSUB_PER_B (N_DIM / 16)          // 1250
#define TOTAL_SUB (B_DIM * NSUB_PER_B)   // 20000

static __device__ inline short f2bf(float x) {
    union { float f; unsigned u; } v; v.f = x;
    unsigned r = v.u + 0x7fffu + ((v.u >> 16) & 1u);   // round-to-nearest-even
    return (short)(r >> 16);
}

// ---------------------------------------------------------------------------
// Kernel 1: fold resize into projections; store bf16 in MFMA fragment order.
// Fragment layout (per matrix): frag id = (mt*4 + c)*64 + lane, 8 bf16 each.
// Element (k,f): mt=k>>4, row=k&15, c=f>>5, kk=f&31, lane=(kk>>3)*16+row, j=kk&7
// ---------------------------------------------------------------------------
__global__ __launch_bounds__(256) void precompute_mats(
    const float* __restrict__ W_rs,   // (128, 384)
    const float* __restrict__ W_e2m,  // (128, 128)
    const float* __restrict__ W_n2m,  // (128, 128)
    unsigned short* __restrict__ wsA,
    unsigned short* __restrict__ wsB)
{
    int idx = blockIdx.x * 256 + threadIdx.x;   // 0..16383
    int k = idx >> 7;
    int f = idx & 127;
    float a = 0.f, b = 0.f;
    for (int m = 0; m < 128; ++m) {
        float wa = W_rs[k * 384 + m];
        float wb = W_rs[k * 384 + 128 + m];
        a += wa * W_e2m[m * 128 + f];
        b += wb * W_n2m[m * 128 + f];
    }
    int mt = k >> 4, row = k & 15;
    int c = f >> 5, kk = f & 31;
    int lane = ((kk >> 3) << 4) | row;
    int j = kk & 7;
    int off = ((mt * 4 + c) * 64 + lane) * 8 + j;
    wsA[off] = (unsigned short)f2bf(a);
    wsB[off] = (unsigned short)f2bf(b);
}

// ---------------------------------------------------------------------------
// Kernel 2: per-(b,k) bias. One block per b, 128 threads.
// ---------------------------------------------------------------------------
__global__ __launch_bounds__(128) void precompute_bias(
    const float* __restrict__ W_rs,
    const float* __restrict__ h_v,     // (B, F)
    const float* __restrict__ b_e2m,
    const float* __restrict__ b_n2m,
    const float* __restrict__ b_rs,
    const float* __restrict__ W_n2m,
    float* __restrict__ bias)          // (B, 128)
{
    __shared__ float nv_s[128];
    int b = blockIdx.x;
    int t = threadIdx.x;
    // phase 1: nv[b,m]
    {
        float nv = b_n2m[t];
        for (int f = 0; f < 128; ++f)
            nv += h_v[b * 128 + f] * W_n2m[t * 128 + f];
        nv_s[t] = nv;
    }
    __syncthreads();
    // phase 2: bias[b,k]
    {
        float acc = b_rs[t];
        for (int m = 0; m < 128; ++m) {
            acc += W_rs[t * 384 + m]       * b_e2m[m];
            acc += W_rs[t * 384 + 128 + m] * b_n2m[m];
            acc += W_rs[t * 384 + 256 + m] * nv_s[m];
        }
        bias[b * 128 + t] = acc;
    }
}

// ---------------------------------------------------------------------------
// Kernel 3: main streaming GEMM.
// Each wave: one 16-wide n-subtile, all 128 output k.
// msg[b,k,n] = sum_f A[k,f]*e_wv[b,f,n] + sum_f B2[k,f]*h_w[b,f,n] + bias[b,k]
// ---------------------------------------------------------------------------
__global__ __launch_bounds__(256) void msg_main(
    const float* __restrict__ e_wv,
    const float* __restrict__ h_w,
    const unsigned short* __restrict__ wsA,
    const unsigned short* __restrict__ wsB,
    const float* __restrict__ bias,
    float* __restrict__ out)
{
    int wid  = threadIdx.x >> 6;
    int lane = threadIdx.x & 63;
    unsigned s = blockIdx.x * 4u + (unsigned)wid;   // 0..19999
    unsigned b = s / NSUB_PER_B;
    unsigned ns = s - b * NSUB_PER_B;
    unsigned n0 = ns * 16u;
    int ln  = lane & 15;     // n offset inside subtile
    int lf8 = lane >> 4;     // 0..3

    const float* Xe = e_wv + (size_t)b * (F_DIM * (size_t)N_DIM) + n0 + ln;
    const float* Xw = h_w  + (size_t)b * (F_DIM * (size_t)N_DIM) + n0 + ln;

    f32x4 acc[8];
#pragma unroll
    for (int mt = 0; mt < 8; ++mt) acc[mt] = (f32x4)(0.f);

    // load + pack X fragments (all 4 K-chunks, both matrices)
    bf16x8 xe[4], xw[4];
#pragma unroll
    for (int c = 0; c < 4; ++c) {
        int fb = c * 32 + lf8 * 8;
        float fe[8], fw[8];
#pragma unroll
        for (int j = 0; j < 8; ++j) {
            fe[j] = Xe[(size_t)(fb + j) * N_DIM];
            fw[j] = Xw[(size_t)(fb + j) * N_DIM];
        }
#pragma unroll
        for (int j = 0; j < 8; ++j) {
            xe[c][j] = f2bf(fe[j]);
            xw[c][j] = f2bf(fw[j]);
        }
    }

    const bf16x8* Afrag = (const bf16x8*)wsA;
    const bf16x8* Bfrag = (const bf16x8*)wsB;
#pragma unroll
    for (int c = 0; c < 4; ++c) {
#pragma unroll
        for (int mt = 0; mt < 8; ++mt) {
            bf16x8 af = Afrag[(mt * 4 + c) * 64 + lane];
            bf16x8 bf = Bfrag[(mt * 4 + c) * 64 + lane];
            acc[mt] = __builtin_amdgcn_mfma_f32_16x16x32_bf16(af, xe[c], acc[mt], 0, 0, 0);
            acc[mt] = __builtin_amdgcn_mfma_f32_16x16x32_bf16(bf, xw[c], acc[mt], 0, 0, 0);
        }
    }

    // epilogue: bias + store. D layout: row=(lane>>4)*4+r, col=lane&15
    float* O = out + (size_t)b * (M_DIM * (size_t)N_DIM) + n0 + ln;
    const f32x4* bias4 = (const f32x4*)(bias + b * 128);
#pragma unroll
    for (int mt = 0; mt < 8; ++mt) {
        f32x4 bb = bias4[mt * 4 + lf8];
#pragma unroll
        for (int r = 0; r < 4; ++r) {
            int k = mt * 16 + lf8 * 4 + r;
            O[(size_t)k * N_DIM] = acc[mt][r] + bb[r];
        }
    }
}

extern "C" void kernel_launch(void* const* d_in, const int* in_sizes, int n_in,
                              void* d_out, int out_size, void* d_ws, size_t ws_size,
                              hipStream_t stream) {
    const float* h_w   = (const float*)d_in[0];
    const float* h_v   = (const float*)d_in[1];
    const float* e_wv  = (const float*)d_in[2];
    const float* W_e2m = (const float*)d_in[3];
    const float* b_e2m = (const float*)d_in[4];
    const float* W_n2m = (const float*)d_in[5];
    const float* b_n2m = (const float*)d_in[6];
    const float* W_rs  = (const float*)d_in[7];
    const float* b_rs  = (const float*)d_in[8];
    float* out = (float*)d_out;

    unsigned short* wsA = (unsigned short*)d_ws;                     // 32 KB
    unsigned short* wsB = wsA + 128 * 128;                           // 32 KB
    float* bias = (float*)((char*)d_ws + 65536);                     // 8 KB

    precompute_mats<<<64, 256, 0, stream>>>(W_rs, W_e2m, W_n2m, wsA, wsB);
    precompute_bias<<<16, 128, 0, stream>>>(W_rs, h_v, b_e2m, b_n2m, b_rs, W_n2m, bias);
    msg_main<<<5000, 256, 0, stream>>>(e_wv, h_w, wsA, wsB, bias, out);
}

// Round 2
// 137.621 us; speedup vs baseline: 1.2360x; 1.2360x over previous
//
#include <hip/hip_runtime.h>
#include <hip/hip_bf16.h>

typedef __attribute__((ext_vector_type(8))) short bf16x8;
typedef __attribute__((ext_vector_type(4))) float f32x4;

#define B_DIM 16
#define F_DIM 128
#define N_DIM 20000
#define M_DIM 128
#define NW 80                      // n-tile per block
#define NSUB 5                     // 16-wide subtiles per tile
#define TILES_PER_B 250            // 20000 / 80
#define MAT_LDS (NSUB * 16 * 128)  // shorts per matrix = 10240 (20480 B)

static __device__ inline unsigned short f2bf(float x) {
    union { float f; unsigned u; } v; v.f = x;
    unsigned r = v.u + 0x7fffu + ((v.u >> 16) & 1u);   // RNE
    return (unsigned short)(r >> 16);
}

// ---------------------------------------------------------------------------
// Kernel 1: fold resize into projections; store bf16 in MFMA fragment order.
// Element (k,f): mt=k>>4, row=k&15, c=f>>5, kk=f&31, lane=(kk>>3)*16+row, j=kk&7
// frag id = (mt*4 + c)*64 + lane, 8 bf16 each.
// ---------------------------------------------------------------------------
__global__ __launch_bounds__(256) void precompute_mats(
    const float* __restrict__ W_rs,   // (128, 384)
    const float* __restrict__ W_e2m,  // (128, 128)
    const float* __restrict__ W_n2m,  // (128, 128)
    unsigned short* __restrict__ wsA,
    unsigned short* __restrict__ wsB)
{
    int idx = blockIdx.x * 256 + threadIdx.x;   // 0..16383
    int k = idx >> 7;
    int f = idx & 127;
    float a = 0.f, b = 0.f;
    for (int m = 0; m < 128; ++m) {
        a += W_rs[k * 384 + m]       * W_e2m[m * 128 + f];
        b += W_rs[k * 384 + 128 + m] * W_n2m[m * 128 + f];
    }
    int mt = k >> 4, row = k & 15;
    int c = f >> 5, kk = f & 31;
    int lane = ((kk >> 3) << 4) | row;
    int j = kk & 7;
    int off = ((mt * 4 + c) * 64 + lane) * 8 + j;
    wsA[off] = f2bf(a);
    wsB[off] = f2bf(b);
}

// ---------------------------------------------------------------------------
// Kernel 2: per-(b,k) bias.
// ---------------------------------------------------------------------------
__global__ __launch_bounds__(128) void precompute_bias(
    const float* __restrict__ W_rs,
    const float* __restrict__ h_v,
    const float* __restrict__ b_e2m,
    const float* __restrict__ b_n2m,
    const float* __restrict__ b_rs,
    const float* __restrict__ W_n2m,
    float* __restrict__ bias)
{
    __shared__ float nv_s[128];
    int b = blockIdx.x;
    int t = threadIdx.x;
    {
        float nv = b_n2m[t];
        for (int f = 0; f < 128; ++f)
            nv += h_v[b * 128 + f] * W_n2m[t * 128 + f];
        nv_s[t] = nv;
    }
    __syncthreads();
    {
        float acc = b_rs[t];
        for (int m = 0; m < 128; ++m) {
            acc += W_rs[t * 384 + m]       * b_e2m[m];
            acc += W_rs[t * 384 + 128 + m] * b_n2m[m];
            acc += W_rs[t * 384 + 256 + m] * nv_s[m];
        }
        bias[b * 128 + t] = acc;
    }
}

// ---------------------------------------------------------------------------
// Kernel 3: main streaming GEMM, LDS-staged.
// Block: 256 thr (4 waves), tile = all 128 f/k x 80 n of one b.
// Wave w owns k rows [32w, 32w+32) (mt = 2w, 2w+1), all 5 n-subtiles.
// LDS layout per matrix: [ns][nn=16][f=128] bf16, byte ^= (nn&7)<<4 on f-bits.
// ---------------------------------------------------------------------------
__global__ __launch_bounds__(256) void msg_main(
    const float* __restrict__ e_wv,
    const float* __restrict__ h_w,
    const unsigned short* __restrict__ wsA,
    const unsigned short* __restrict__ wsB,
    const float* __restrict__ bias,
    float* __restrict__ out)
{
    __shared__ unsigned short lds[2 * MAT_LDS];   // 40960 B

    int tid = threadIdx.x;
    int w   = tid >> 6;
    int l   = tid & 63;
    int blk = blockIdx.x;
    int b   = blk / TILES_PER_B;
    int n0  = (blk - b * TILES_PER_B) * NW;

    const float* eb = e_wv + (size_t)b * (F_DIM * (size_t)N_DIM) + n0;
    const float* wb = h_w  + (size_t)b * (F_DIM * (size_t)N_DIM) + n0;

    // ---- staging: load 128x80 f32 of each matrix, cvt bf16, transpose to LDS
    // per-thread: 5 units (fp, nq); fp = f/2 pair index, nq = n/4 quad index.
    // lane map: fp = (widx&3)*16 + (l>>2), nq = (widx>>2)*4 + (l&3)
    f32x4 ve[5][2], vw[5][2];
    int fp_[5], nq_[5];
#pragma unroll
    for (int i = 0; i < 5; ++i) {
        int widx = i * 4 + w;
        int fp = (widx & 3) * 16 + (l >> 2);
        int nq = (widx >> 2) * 4 + (l & 3);
        fp_[i] = fp; nq_[i] = nq;
        const float* pe0 = eb + (size_t)(2 * fp)     * N_DIM + 4 * nq;
        const float* pe1 = eb + (size_t)(2 * fp + 1) * N_DIM + 4 * nq;
        ve[i][0] = *(const f32x4*)pe0;
        ve[i][1] = *(const f32x4*)pe1;
    }
#pragma unroll
    for (int i = 0; i < 5; ++i) {
        const float* pw0 = wb + (size_t)(2 * fp_[i])     * N_DIM + 4 * nq_[i];
        const float* pw1 = wb + (size_t)(2 * fp_[i] + 1) * N_DIM + 4 * nq_[i];
        vw[i][0] = *(const f32x4*)pw0;
        vw[i][1] = *(const f32x4*)pw1;
    }

    char* ldsc = (char*)lds;
#pragma unroll
    for (int i = 0; i < 5; ++i) {
        int fp = fp_[i], nq = nq_[i];
        int ns = nq >> 2;
        int nnb = (nq & 3) * 4;
#pragma unroll
        for (int q = 0; q < 4; ++q) {
            int nn = nnb + q;
            unsigned fo = (unsigned)(fp * 4) ^ (unsigned)((nn & 7) << 4);
            unsigned off = (unsigned)(ns * 4096 + nn * 256) + fo;
            unsigned pe = (unsigned)f2bf(ve[i][0][q]) | ((unsigned)f2bf(ve[i][1][q]) << 16);
            unsigned pw = (unsigned)f2bf(vw[i][0][q]) | ((unsigned)f2bf(vw[i][1][q]) << 16);
            *(unsigned*)(ldsc + off) = pe;
            *(unsigned*)(ldsc + 2 * MAT_LDS + off) = pw;   // byte offset of mat 1
        }
    }
    __syncthreads();

    // ---- compute
    int ln = l & 15, g = l >> 4;
    f32x4 acc[2][NSUB];
#pragma unroll
    for (int mtL = 0; mtL < 2; ++mtL)
#pragma unroll
        for (int ns = 0; ns < NSUB; ++ns) acc[mtL][ns] = (f32x4)(0.f);

    const bf16x8* Af = (const bf16x8*)wsA;
    const bf16x8* Bf = (const bf16x8*)wsB;
    const char* ldse = ldsc;
    const char* ldsw = ldsc + 2 * MAT_LDS;
    unsigned rbase = (unsigned)(ln * 256);
    unsigned rx = (unsigned)((ln & 7) << 4);

#pragma unroll
    for (int c = 0; c < 4; ++c) {
        bf16x8 a0 = Af[((2 * w + 0) * 4 + c) * 64 + l];
        bf16x8 a1 = Af[((2 * w + 1) * 4 + c) * 64 + l];
        bf16x8 b0 = Bf[((2 * w + 0) * 4 + c) * 64 + l];
        bf16x8 b1 = Bf[((2 * w + 1) * 4 + c) * 64 + l];
        unsigned fbyte = (unsigned)((c * 32 + g * 8) * 2) ^ rx;
#pragma unroll
        for (int ns = 0; ns < NSUB; ++ns) {
            bf16x8 xe = *(const bf16x8*)(ldse + ns * 4096 + rbase + fbyte);
            bf16x8 xw = *(const bf16x8*)(ldsw + ns * 4096 + rbase + fbyte);
            acc[0][ns] = __builtin_amdgcn_mfma_f32_16x16x32_bf16(a0, xe, acc[0][ns], 0, 0, 0);
            acc[0][ns] = __builtin_amdgcn_mfma_f32_16x16x32_bf16(b0, xw, acc[0][ns], 0, 0, 0);
            acc[1][ns] = __builtin_amdgcn_mfma_f32_16x16x32_bf16(a1, xe, acc[1][ns], 0, 0, 0);
            acc[1][ns] = __builtin_amdgcn_mfma_f32_16x16x32_bf16(b1, xw, acc[1][ns], 0, 0, 0);
        }
    }

    // ---- epilogue: bias + store (D: col=lane&15 -> n, row=(lane>>4)*4+r -> k)
    const f32x4* bias4 = (const f32x4*)(bias + b * 128);
    float* O = out + (size_t)b * (M_DIM * (size_t)N_DIM) + n0 + ln;
#pragma unroll
    for (int mtL = 0; mtL < 2; ++mtL) {
        int mt = 2 * w + mtL;
        f32x4 bb = bias4[mt * 4 + g];
#pragma unroll
        for (int ns = 0; ns < NSUB; ++ns) {
#pragma unroll
            for (int r = 0; r < 4; ++r) {
                int k = mt * 16 + g * 4 + r;
                O[(size_t)k * N_DIM + ns * 16] = acc[mtL][ns][r] + bb[r];
            }
        }
    }
}

extern "C" void kernel_launch(void* const* d_in, const int* in_sizes, int n_in,
                              void* d_out, int out_size, void* d_ws, size_t ws_size,
                              hipStream_t stream) {
    const float* h_w   = (const float*)d_in[0];
    const float* h_v   = (const float*)d_in[1];
    const float* e_wv  = (const float*)d_in[2];
    const float* W_e2m = (const float*)d_in[3];
    const float* b_e2m = (const float*)d_in[4];
    const float* W_n2m = (const float*)d_in[5];
    const float* b_n2m = (const float*)d_in[6];
    const float* W_rs  = (const float*)d_in[7];
    const float* b_rs  = (const float*)d_in[8];
    float* out = (float*)d_out;

    unsigned short* wsA = (unsigned short*)d_ws;                     // 32 KB
    unsigned short* wsB = wsA + 128 * 128;                           // 32 KB
    float* bias = (float*)((char*)d_ws + 65536);                     // 8 KB

    precompute_mats<<<64, 256, 0, stream>>>(W_rs, W_e2m, W_n2m, wsA, wsB);
    precompute_bias<<<16, 128, 0, stream>>>(W_rs, h_v, b_e2m, b_n2m, b_rs, W_n2m, bias);
    msg_main<<<16 * TILES_PER_B, 256, 0, stream>>>(e_wv, h_w, wsA, wsB, bias, out);
}

// Round 3
// 136.609 us; speedup vs baseline: 1.2452x; 1.0074x over previous
//
#include <hip/hip_runtime.h>
#include <hip/hip_bf16.h>

typedef __attribute__((ext_vector_type(8))) short bf16x8;
typedef __attribute__((ext_vector_type(4))) float f32x4;

#define B_DIM 16
#define F_DIM 128
#define N_DIM 20000
#define M_DIM 128
#define NW 80                      // n-tile per block
#define NSUB 5                     // 16-wide subtiles per tile
#define TILES_PER_B 250            // 20000 / 80
#define NBLK (16 * TILES_PER_B)    // 4000
#define MAT_LDS (NSUB * 16 * 128)  // shorts per matrix = 10240 (20480 B)

static __device__ inline unsigned short f2bf(float x) {
    union { float f; unsigned u; } v; v.f = x;
    unsigned r = v.u + 0x7fffu + ((v.u >> 16) & 1u);   // RNE
    return (unsigned short)(r >> 16);
}

// ---------------------------------------------------------------------------
// Kernel 1: fold resize into projections; store bf16 in MFMA fragment order.
// Element (k,f): mt=k>>4, row=k&15, c=f>>5, kk=f&31, lane=(kk>>3)*16+row, j=kk&7
// frag id = (mt*4 + c)*64 + lane, 8 bf16 each.
// ---------------------------------------------------------------------------
__global__ __launch_bounds__(256) void precompute_mats(
    const float* __restrict__ W_rs,   // (128, 384)
    const float* __restrict__ W_e2m,  // (128, 128)
    const float* __restrict__ W_n2m,  // (128, 128)
    unsigned short* __restrict__ wsA,
    unsigned short* __restrict__ wsB)
{
    int idx = blockIdx.x * 256 + threadIdx.x;   // 0..16383
    int k = idx >> 7;
    int f = idx & 127;
    float a = 0.f, b = 0.f;
    for (int m = 0; m < 128; ++m) {
        a += W_rs[k * 384 + m]       * W_e2m[m * 128 + f];
        b += W_rs[k * 384 + 128 + m] * W_n2m[m * 128 + f];
    }
    int mt = k >> 4, row = k & 15;
    int c = f >> 5, kk = f & 31;
    int lane = ((kk >> 3) << 4) | row;
    int j = kk & 7;
    int off = ((mt * 4 + c) * 64 + lane) * 8 + j;
    wsA[off] = f2bf(a);
    wsB[off] = f2bf(b);
}

// ---------------------------------------------------------------------------
// Kernel 2: per-(b,k) bias.
// ---------------------------------------------------------------------------
__global__ __launch_bounds__(128) void precompute_bias(
    const float* __restrict__ W_rs,
    const float* __restrict__ h_v,
    const float* __restrict__ b_e2m,
    const float* __restrict__ b_n2m,
    const float* __restrict__ b_rs,
    const float* __restrict__ W_n2m,
    float* __restrict__ bias)
{
    __shared__ float nv_s[128];
    int b = blockIdx.x;
    int t = threadIdx.x;
    {
        float nv = b_n2m[t];
        for (int f = 0; f < 128; ++f)
            nv += h_v[b * 128 + f] * W_n2m[t * 128 + f];
        nv_s[t] = nv;
    }
    __syncthreads();
    {
        float acc = b_rs[t];
        for (int m = 0; m < 128; ++m) {
            acc += W_rs[t * 384 + m]       * b_e2m[m];
            acc += W_rs[t * 384 + 128 + m] * b_n2m[m];
            acc += W_rs[t * 384 + 256 + m] * nv_s[m];
        }
        bias[b * 128 + t] = acc;
    }
}

// ---------------------------------------------------------------------------
// Kernel 3: main streaming GEMM, LDS-staged.
// Block: 256 thr (4 waves), tile = all 128 f/k x 80 n of one b.
// XCD-swizzled blockIdx: each XCD owns a contiguous 500-tile chunk so
// adjacent tiles (sharing 128B-line halves + weight frags) are L2-local.
// launch_bounds(256,4): VGPR cap 128 so all 20 staging loads stay in flight.
// ---------------------------------------------------------------------------
__global__ __launch_bounds__(256, 4) void msg_main(
    const float* __restrict__ e_wv,
    const float* __restrict__ h_w,
    const unsigned short* __restrict__ wsA,
    const unsigned short* __restrict__ wsB,
    const float* __restrict__ bias,
    float* __restrict__ out)
{
    __shared__ unsigned short lds[2 * MAT_LDS];   // 40960 B

    int tid = threadIdx.x;
    int w   = tid >> 6;
    int l   = tid & 63;
    // bijective XCD swizzle: 4000 % 8 == 0, chunk = 500 consecutive tiles/XCD
    int blk0 = blockIdx.x;
    int blk  = (blk0 & 7) * (NBLK / 8) + (blk0 >> 3);
    int b   = blk / TILES_PER_B;
    int n0  = (blk - b * TILES_PER_B) * NW;

    const float* eb = e_wv + (size_t)b * (F_DIM * (size_t)N_DIM) + n0;
    const float* wb = h_w  + (size_t)b * (F_DIM * (size_t)N_DIM) + n0;

    // ---- staging: issue ALL 20 dwordx4 loads first, then cvt+transpose->LDS
    // lane map: fp = (widx&3)*16 + (l>>2), nq = (widx>>2)*4 + (l&3)
    f32x4 ve[5][2], vw[5][2];
    int fp_[5], nq_[5];
#pragma unroll
    for (int i = 0; i < 5; ++i) {
        int widx = i * 4 + w;
        int fp = (widx & 3) * 16 + (l >> 2);
        int nq = (widx >> 2) * 4 + (l & 3);
        fp_[i] = fp; nq_[i] = nq;
        ve[i][0] = *(const f32x4*)(eb + (size_t)(2 * fp)     * N_DIM + 4 * nq);
        ve[i][1] = *(const f32x4*)(eb + (size_t)(2 * fp + 1) * N_DIM + 4 * nq);
    }
#pragma unroll
    for (int i = 0; i < 5; ++i) {
        vw[i][0] = *(const f32x4*)(wb + (size_t)(2 * fp_[i])     * N_DIM + 4 * nq_[i]);
        vw[i][1] = *(const f32x4*)(wb + (size_t)(2 * fp_[i] + 1) * N_DIM + 4 * nq_[i]);
    }

    char* ldsc = (char*)lds;
#pragma unroll
    for (int i = 0; i < 5; ++i) {
        int fp = fp_[i], nq = nq_[i];
        int ns = nq >> 2;
        int nnb = (nq & 3) * 4;
#pragma unroll
        for (int q = 0; q < 4; ++q) {
            int nn = nnb + q;
            unsigned fo = (unsigned)(fp * 4) ^ (unsigned)((nn & 7) << 4);
            unsigned off = (unsigned)(ns * 4096 + nn * 256) + fo;
            unsigned pe = (unsigned)f2bf(ve[i][0][q]) | ((unsigned)f2bf(ve[i][1][q]) << 16);
            unsigned pw = (unsigned)f2bf(vw[i][0][q]) | ((unsigned)f2bf(vw[i][1][q]) << 16);
            *(unsigned*)(ldsc + off) = pe;
            *(unsigned*)(ldsc + 2 * MAT_LDS + off) = pw;
        }
    }
    __syncthreads();

    // ---- compute: wave w owns k rows [32w,32w+32) (mt = 2w,2w+1)
    int ln = l & 15, g = l >> 4;
    f32x4 acc[2][NSUB];
#pragma unroll
    for (int mtL = 0; mtL < 2; ++mtL)
#pragma unroll
        for (int ns = 0; ns < NSUB; ++ns) acc[mtL][ns] = (f32x4)(0.f);

    const bf16x8* Af = (const bf16x8*)wsA;
    const bf16x8* Bf = (const bf16x8*)wsB;
    const char* ldse = ldsc;
    const char* ldsw = ldsc + 2 * MAT_LDS;
    unsigned rbase = (unsigned)(ln * 256);
    unsigned rx = (unsigned)((ln & 7) << 4);

#pragma unroll
    for (int c = 0; c < 4; ++c) {
        bf16x8 a0 = Af[((2 * w + 0) * 4 + c) * 64 + l];
        bf16x8 a1 = Af[((2 * w + 1) * 4 + c) * 64 + l];
        bf16x8 b0 = Bf[((2 * w + 0) * 4 + c) * 64 + l];
        bf16x8 b1 = Bf[((2 * w + 1) * 4 + c) * 64 + l];
        unsigned fbyte = (unsigned)((c * 32 + g * 8) * 2) ^ rx;
#pragma unroll
        for (int ns = 0; ns < NSUB; ++ns) {
            bf16x8 xe = *(const bf16x8*)(ldse + ns * 4096 + rbase + fbyte);
            bf16x8 xw = *(const bf16x8*)(ldsw + ns * 4096 + rbase + fbyte);
            acc[0][ns] = __builtin_amdgcn_mfma_f32_16x16x32_bf16(a0, xe, acc[0][ns], 0, 0, 0);
            acc[0][ns] = __builtin_amdgcn_mfma_f32_16x16x32_bf16(b0, xw, acc[0][ns], 0, 0, 0);
            acc[1][ns] = __builtin_amdgcn_mfma_f32_16x16x32_bf16(a1, xe, acc[1][ns], 0, 0, 0);
            acc[1][ns] = __builtin_amdgcn_mfma_f32_16x16x32_bf16(b1, xw, acc[1][ns], 0, 0, 0);
        }
    }

    // ---- epilogue: bias + nontemporal store (out never re-read)
    const f32x4* bias4 = (const f32x4*)(bias + b * 128);
    float* O = out + (size_t)b * (M_DIM * (size_t)N_DIM) + n0 + ln;
#pragma unroll
    for (int mtL = 0; mtL < 2; ++mtL) {
        int mt = 2 * w + mtL;
        f32x4 bb = bias4[mt * 4 + g];
#pragma unroll
        for (int ns = 0; ns < NSUB; ++ns) {
#pragma unroll
            for (int r = 0; r < 4; ++r) {
                int k = mt * 16 + g * 4 + r;
                __builtin_nontemporal_store(acc[mtL][ns][r] + bb[r],
                                            O + (size_t)k * N_DIM + ns * 16);
            }
        }
    }
}

extern "C" void kernel_launch(void* const* d_in, const int* in_sizes, int n_in,
                              void* d_out, int out_size, void* d_ws, size_t ws_size,
                              hipStream_t stream) {
    const float* h_w   = (const float*)d_in[0];
    const float* h_v   = (const float*)d_in[1];
    const float* e_wv  = (const float*)d_in[2];
    const float* W_e2m = (const float*)d_in[3];
    const float* b_e2m = (const float*)d_in[4];
    const float* W_n2m = (const float*)d_in[5];
    const float* b_n2m = (const float*)d_in[6];
    const float* W_rs  = (const float*)d_in[7];
    const float* b_rs  = (const float*)d_in[8];
    float* out = (float*)d_out;

    unsigned short* wsA = (unsigned short*)d_ws;                     // 32 KB
    unsigned short* wsB = wsA + 128 * 128;                           // 32 KB
    float* bias = (float*)((char*)d_ws + 65536);                     // 8 KB

    precompute_mats<<<64, 256, 0, stream>>>(W_rs, W_e2m, W_n2m, wsA, wsB);
    precompute_bias<<<16, 128, 0, stream>>>(W_rs, h_v, b_e2m, b_n2m, b_rs, W_n2m, bias);
    msg_main<<<NBLK, 256, 0, stream>>>(e_wv, h_w, wsA, wsB, bias, out);
}